// Round 9
// baseline (38.455 us; speedup 1.0000x reference)
//
#include <hip/hip_runtime.h>

#define BATCH 8
#define NPTS  4096
#define BLOCK 256
#define Q     16             // query points per thread (BLOCK*Q == NPTS)
#define NT    32             // target chunks  (NT*CHUNK == NPTS)
#define CHUNK 128            // targets staged in LDS per block
#define NPAIR (CHUNK / 2)    // 64 target PAIRS in LDS
#define NPER  32768          // BATCH*NPTS points per cloud
#define NQTOT (2 * NPER)     // 65536 query slots (both passes)

typedef float f2 __attribute__((ext_vector_type(2)));

// ws layout:
//   float  partial[NT][65536]: per-chunk min DIST (already sqrt'd)   (8 MB)
//   double bsum[64]          : per-block partial sums from reduce1

// K1: grid (1, NT, 16) = 512 blocks. Each thread owns Q=16 queries; block
// stages CHUNK=128 targets in LDS as float2-pairs [(x0,x1,y0,y1),(z0,z1,w0,w1)].
// Per target-pair per query: 3 v_pk_fma_f32 + 1 v_min3_f32 (2 instr/pair).
// Writes sqrt'd chunk-min to private partial slice. No atomics, no init.
__global__ __launch_bounds__(BLOCK) void chamfer_min_kernel(
    const float* __restrict__ pred, const float* __restrict__ gt,
    float* __restrict__ partial)
{
    const int z    = blockIdx.z;                      // pass*8 + b
    const int b    = z & 7;
    const int pass = z >> 3;
    const float* query  = (pass ? gt : pred) + (size_t)b * NPTS * 3;
    const float* target = (pass ? pred : gt) + (size_t)b * NPTS * 3;

    __shared__ float4 sA[NPAIR];                      // (x0,x1,y0,y1)
    __shared__ float4 sB[NPAIR];                      // (z0,z1,w0,w1)

    const int tid = threadIdx.x;
    const int c0  = blockIdx.y * CHUNK;

    if (tid < NPAIR) {
        const float* t0 = target + (size_t)(c0 + 2 * tid) * 3;
        const float x0 = t0[0], y0 = t0[1], z0 = t0[2];
        const float x1 = t0[3], y1 = t0[4], z1 = t0[5];
        const float w0 = fmaf(x0, x0, fmaf(y0, y0, z0 * z0));
        const float w1 = fmaf(x1, x1, fmaf(y1, y1, z1 * z1));
        sA[tid] = make_float4(x0, x1, y0, y1);
        sB[tid] = make_float4(z0, z1, w0, w1);
    }

    f2 nx[Q], ny[Q], nz[Q];
    float p2[Q], mn[Q];
#pragma unroll
    for (int i = 0; i < Q; ++i) {
        const float* qp = query + (size_t)(i * BLOCK + tid) * 3;
        const float x = qp[0], y = qp[1], zz = qp[2];
        nx[i] = (f2){-2.0f * x, -2.0f * x};
        ny[i] = (f2){-2.0f * y, -2.0f * y};
        nz[i] = (f2){-2.0f * zz, -2.0f * zz};
        p2[i] = fmaf(x, x, fmaf(y, y, zz * zz));
        mn[i] = 3.0e38f;
    }
    __syncthreads();

#pragma unroll 2
    for (int j = 0; j < NPAIR; ++j) {
        const float4 a  = sA[j];
        const float4 bb = sB[j];
        const f2 gx = {a.x, a.y};
        const f2 gy = {a.z, a.w};
        const f2 gz = {bb.x, bb.y};
        const f2 gw = {bb.z, bb.w};                   // (g2_0, g2_1)
#pragma unroll
        for (int i = 0; i < Q; ++i) {
            f2 d = __builtin_elementwise_fma(gx, nx[i], gw);
            d = __builtin_elementwise_fma(gy, ny[i], d);
            d = __builtin_elementwise_fma(gz, nz[i], d);
            mn[i] = fminf(mn[i], fminf(d.x, d.y));    // -> v_min3_f32
        }
    }

    float* dst = partial + (size_t)blockIdx.y * NQTOT + (size_t)z * NPTS;
#pragma unroll
    for (int i = 0; i < Q; ++i) {
        dst[i * BLOCK + tid] = sqrtf(fmaxf(p2[i] + mn[i], 0.0f));
    }
}

// K2: 64 blocks x 1024. Thread j: min over NT chunk-partials (already sqrt'd),
// deterministic LDS tree-sum in double -> bsum[block].
__global__ __launch_bounds__(1024) void reduce1_kernel(
    const float* __restrict__ partial, double* __restrict__ bsum)
{
    const int tid = threadIdx.x;
    const int j   = blockIdx.x * 1024 + tid;          // query slot 0..65535

    float m = 3.0e38f;
#pragma unroll 4
    for (int c = 0; c < NT; c += 2) {
        const float a0 = partial[(size_t)c * NQTOT + j];
        const float a1 = partial[(size_t)(c + 1) * NQTOT + j];
        m = fminf(m, fminf(a0, a1));
    }

    __shared__ double sd[1024];
    sd[tid] = (double)m;
    __syncthreads();
    for (int off = 512; off > 0; off >>= 1) {
        if (tid < off) sd[tid] += sd[tid + off];
        __syncthreads();
    }
    if (tid == 0) bsum[blockIdx.x] = sd[0];
}

// K3: one wave sums the 64 block sums (deterministic shuffle tree).
__global__ __launch_bounds__(64) void reduce2_kernel(
    const double* __restrict__ bsum, float* __restrict__ out)
{
    double v = bsum[threadIdx.x];
#pragma unroll
    for (int off = 32; off > 0; off >>= 1) {
        v += __shfl_down(v, off);
    }
    if (threadIdx.x == 0) out[0] = (float)(v / (double)NPER);
}

extern "C" void kernel_launch(void* const* d_in, const int* in_sizes, int n_in,
                              void* d_out, int out_size, void* d_ws, size_t ws_size,
                              hipStream_t stream) {
    const float* pred = (const float*)d_in[0];
    const float* gt   = (const float*)d_in[1];

    float*  partial = (float*)d_ws;                         // 8 MB
    double* bsum    = (double*)(partial + (size_t)NT * NQTOT);

    dim3 grid(1, NT, 2 * BATCH);
    chamfer_min_kernel<<<grid, BLOCK, 0, stream>>>(pred, gt, partial);

    reduce1_kernel<<<NQTOT / 1024, 1024, 0, stream>>>(partial, bsum);
    reduce2_kernel<<<1, 64, 0, stream>>>(bsum, (float*)d_out);
}